// Round 1
// baseline (811.075 us; speedup 1.0000x reference)
//
#include <hip/hip_runtime.h>

// Layout of d_ws:
//   [0..15]   : 2 doubles  -> acc[0]=sum(R_free^2), acc[1]=sum(F_free^2)
//   [16.. )   : 3*N floats -> F_int
//
// All fp32 element math matches the jnp fp32 reference; reductions in fp64.

__global__ void elem_kernel(const float* __restrict__ pred,
                            const float* __restrict__ u_c,
                            const float* __restrict__ theta_c,
                            const float* __restrict__ len,
                            const float* __restrict__ pE,
                            const float* __restrict__ pA,
                            const float* __restrict__ pI,
                            const float* __restrict__ dir,
                            const int*   __restrict__ conn,
                            float* __restrict__ Fint,
                            int E) {
    int e = blockIdx.x * blockDim.x + threadIdx.x;
    if (e >= E) return;

    int na = conn[2 * e + 0];
    int nb = conn[2 * e + 1];
    float c = dir[3 * e + 0];
    float s = dir[3 * e + 2];
    float L = len[e];
    float Ee = pE[e];
    float EA = Ee * pA[e];
    float EI = Ee * pI[e];

    float uc = u_c[0];
    float tc = theta_c[0];

    float a0 = pred[3 * na + 0] * uc;
    float a1 = pred[3 * na + 1] * uc;
    float a2 = pred[3 * na + 2] * tc;
    float b0 = pred[3 * nb + 0] * uc;
    float b1 = pred[3 * nb + 1] * uc;
    float b2 = pred[3 * nb + 2] * tc;

    float u_A  =  c * a0 + s * a1;
    float w_A  = -s * a0 + c * a1;
    float th_A = -a2;
    float u_B  =  c * b0 + s * b1;
    float w_B  = -s * b0 + c * b1;
    float th_B = -b2;

    float invL  = 1.0f / L;
    float ea_l  = EA * invL;           // AXIAL_WEIGHT = 1.0
    float ei_l  = EI * invL;
    float ei_l2 = ei_l  * invL;
    float ei_l3 = ei_l2 * invL;

    float dw = w_A - w_B;
    float f0 = ea_l * (u_A - u_B);
    float f1 = 12.0f * ei_l3 * dw + 6.0f * ei_l2 * (th_A + th_B);
    float f2 = 6.0f * ei_l2 * dw + 4.0f * ei_l * th_A + 2.0f * ei_l * th_B;
    float f5 = 6.0f * ei_l2 * dw + 2.0f * ei_l * th_A + 4.0f * ei_l * th_B;

    float fA0 = c * f0 - s * f1;
    float fA1 = s * f0 + c * f1;
    // fB0 = c*(-f0) - s*(-f1) = -fA0 ; fB1 = -fA1

    atomicAdd(&Fint[3 * na + 0],  fA0);
    atomicAdd(&Fint[3 * na + 1],  fA1);
    atomicAdd(&Fint[3 * na + 2], -f2);
    atomicAdd(&Fint[3 * nb + 0], -fA0);
    atomicAdd(&Fint[3 * nb + 1], -fA1);
    atomicAdd(&Fint[3 * nb + 2], -f5);
}

__global__ void node_kernel(const float* __restrict__ Fint,
                            const float* __restrict__ Fext,
                            const float* __restrict__ bcd,
                            const float* __restrict__ bcr,
                            double* __restrict__ acc,
                            int N) {
    int i = blockIdx.x * blockDim.x + threadIdx.x;
    double num = 0.0, den = 0.0;
    if (i < N) {
        float md = 1.0f - bcd[i];
        float mr = 1.0f - bcr[i];
        float e0 = Fext[3 * i + 0];
        float e1 = Fext[3 * i + 1];
        float e2 = Fext[3 * i + 2];
        float r0 = (Fint[3 * i + 0] - e0) * md;
        float r1 = (Fint[3 * i + 1] - e1) * md;
        float r2 = (Fint[3 * i + 2] - e2) * mr;
        float g0 = e0 * md;
        float g1 = e1 * md;
        float g2 = e2 * mr;
        num = (double)r0 * r0 + (double)r1 * r1 + (double)r2 * r2;
        den = (double)g0 * g0 + (double)g1 * g1 + (double)g2 * g2;
    }
    // wave (64-lane) butterfly reduce
    #pragma unroll
    for (int off = 32; off > 0; off >>= 1) {
        num += __shfl_down(num, off, 64);
        den += __shfl_down(den, off, 64);
    }
    __shared__ double sn[4], sd[4];
    int lane = threadIdx.x & 63;
    int wv   = threadIdx.x >> 6;
    if (lane == 0) { sn[wv] = num; sd[wv] = den; }
    __syncthreads();
    if (threadIdx.x == 0) {
        double tn = 0.0, td = 0.0;
        int nw = blockDim.x >> 6;
        for (int w = 0; w < nw; ++w) { tn += sn[w]; td += sd[w]; }
        atomicAdd(&acc[0], tn);
        atomicAdd(&acc[1], td);
    }
}

__global__ void final_kernel(const double* __restrict__ acc, float* __restrict__ out) {
    double den = acc[1];
    if (den < 1e-30) den = 1e-30;
    out[0] = (float)(acc[0] / den);
}

extern "C" void kernel_launch(void* const* d_in, const int* in_sizes, int n_in,
                              void* d_out, int out_size, void* d_ws, size_t ws_size,
                              hipStream_t stream) {
    const float* pred    = (const float*)d_in[0];
    const float* u_c     = (const float*)d_in[1];
    const float* theta_c = (const float*)d_in[2];
    const float* len     = (const float*)d_in[3];
    const float* pE      = (const float*)d_in[4];
    const float* pA      = (const float*)d_in[5];
    const float* pI      = (const float*)d_in[6];
    const float* dir     = (const float*)d_in[7];
    const float* Fext    = (const float*)d_in[8];
    const float* bcd     = (const float*)d_in[9];
    const float* bcr     = (const float*)d_in[10];
    const int*   conn    = (const int*)d_in[11];

    int N = in_sizes[0] / 3;
    int E = in_sizes[3];

    double* acc  = (double*)d_ws;
    float*  Fint = (float*)((char*)d_ws + 16);

    hipMemsetAsync(d_ws, 0, 16 + (size_t)3 * N * sizeof(float), stream);

    elem_kernel<<<(E + 255) / 256, 256, 0, stream>>>(
        pred, u_c, theta_c, len, pE, pA, pI, dir, conn, Fint, E);

    node_kernel<<<(N + 255) / 256, 256, 0, stream>>>(
        Fint, Fext, bcd, bcr, acc, N);

    final_kernel<<<1, 1, 0, stream>>>(acc, (float*)d_out);
}